// Round 3
// baseline (548.621 us; speedup 1.0000x reference)
//
#include <hip/hip_runtime.h>

// out[b,c,n] = x[b,c, px*NY+py], px=trunc(clip(coords[b,n,1]*(NX-1),0,NX)),
//                                py=trunc(clip(coords[b,n,0]*(NY-1),0,NY))
//
// R6: the 4-pass staged pipeline (mark/scan/transpose/gather) moves >=650MB
// and three rounds of memory-pattern tuning were neutral -> the structure is
// the cost. Replace with ONE reuse-aware direct gather:
//   - block = (batch b, channel-half cg, n-tile of 1024 samples)
//   - bid&7 = b pins each batch to one XCD; the 32 co-XCD blocks of a
//     channel-half sweep channels in near-lockstep -> active working set is
//     ~1-3 planes (256KB each) << 4MB L2; each plane leaves HBM once.
//   - sequential register prefetch of plane c+3 (asm keep-alive) makes the
//     HBM side pure streaming; drift is self-correcting (leaders miss L2
//     and slow down).
//   - idx held in 4 VGPRs per thread (same 4 samples for all 64 channels).
// Traffic: x 268MB seq + out 134MB + coords ~4MB ~= 405MB ~= 64us floor.
#define B_  8
#define C_  128
#define NX_ 256
#define NY_ 256
#define N_  32768
#define PLANE_ (NX_ * NY_)                       // 65536

typedef float f32x4 __attribute__((ext_vector_type(4)));

__device__ __forceinline__ int sample_idx(const float* __restrict__ coords, int b, int n) {
    const float2 cc = *reinterpret_cast<const float2*>(coords + ((size_t)b * N_ + n) * 2);
    const int px = (int)fminf(fmaxf(cc.y * (float)(NX_ - 1), 0.0f), (float)NX_);
    const int py = (int)fminf(fmaxf(cc.x * (float)(NY_ - 1), 0.0f), (float)NY_);
    return min(px * NY_ + py, PLANE_ - 1);
}

// grid = B_ * 2 * (N_/1024) = 512 blocks (2/CU, 8 waves/CU)
__global__ __launch_bounds__(256, 2) void gather_direct(const float* __restrict__ x,
                                                        const float* __restrict__ coords,
                                                        float* __restrict__ out) {
    const int bid = blockIdx.x;
    const int b   = bid & 7;                     // batch == XCD affinity
    const int cg  = (bid >> 3) & 1;              // channel half: 64 channels
    const int nt  = bid >> 4;                    // 0..31 n-tile
    const int n0  = nt << 10;                    // 1024 samples per block
    const int t   = threadIdx.x;

    // 4 sample indices per thread, register-resident for all 64 channels.
    int idx[4];
    #pragma unroll
    for (int k = 0; k < 4; ++k) idx[k] = sample_idx(coords, b, n0 + t + 256 * k);

    const float* __restrict__ xb = x + ((size_t)b * C_ + (size_t)cg * 64) * PLANE_;
    float* __restrict__ ob = out + ((size_t)b * C_ + (size_t)cg * 64) * N_ + n0;

    // block nt prefetches floats [nt*2048, nt*2048+2048) of each plane; the
    // 32 co-XCD blocks jointly cover the full 256KB plane sequentially.
    const float* __restrict__ pfb = xb + nt * 2048 + t * 8;

    #pragma unroll 2
    for (int c = 0; c < 64; ++c) {
        // prefetch plane c+3 into L2 (sequential HBM), keep loads live
        const int cpf = (c + 3 < 64) ? (c + 3) : 63;
        {
            const f32x4 p0 = *reinterpret_cast<const f32x4*>(pfb + (size_t)cpf * PLANE_);
            const f32x4 p1 = *reinterpret_cast<const f32x4*>(pfb + (size_t)cpf * PLANE_ + 4);
            asm volatile("" :: "v"(p0), "v"(p1));
        }
        // gather 4 samples from plane c (L2-resident)
        const float* __restrict__ xp = xb + (size_t)c * PLANE_;
        float v[4];
        #pragma unroll
        for (int k = 0; k < 4; ++k) v[k] = xp[idx[k]];
        // coalesced 256B nontemporal stores along n
        #pragma unroll
        for (int k = 0; k < 4; ++k)
            __builtin_nontemporal_store(v[k], ob + (size_t)c * N_ + t + 256 * k);
    }
}

extern "C" void kernel_launch(void* const* d_in, const int* in_sizes, int n_in,
                              void* d_out, int out_size, void* d_ws, size_t ws_size,
                              hipStream_t stream) {
    const float* x      = (const float*)d_in[0];
    const float* coords = (const float*)d_in[1];
    float* out          = (float*)d_out;
    gather_direct<<<B_ * 2 * (N_ / 1024), 256, 0, stream>>>(x, coords, out);
}